// Round 14
// baseline (680.497 us; speedup 1.0000x reference)
//
#include <hip/hip_runtime.h>

#define HD 128

typedef __attribute__((ext_vector_type(8))) short bf16x8;
typedef __attribute__((ext_vector_type(4))) float f32x4;

// ---- bf16 helpers ----------------------------------------------------------
__device__ __forceinline__ unsigned rne16(float x) {
  unsigned u = __builtin_bit_cast(unsigned, x);
  return (u + 0x7fffu + ((u >> 16) & 1u)) >> 16;
}
__device__ __forceinline__ unsigned pk2(float a, float b) {  // HW v_cvt_pk_bf16_f32
  unsigned r;
  asm("v_cvt_pk_bf16_f32 %0, %1, %2" : "=v"(r) : "v"(a), "v"(b));
  return r;
}
__device__ __forceinline__ float blo(unsigned u) { return __builtin_bit_cast(float, u << 16); }
__device__ __forceinline__ float bhi(unsigned u) { return __builtin_bit_cast(float, u & 0xffff0000u); }
__device__ __forceinline__ float bval(unsigned h16) { return __builtin_bit_cast(float, h16 << 16); }

__device__ __forceinline__ void bsplit(float v, unsigned short& hi, unsigned short& lo) {
  unsigned h = rne16(v);
  hi = (unsigned short)h;
  lo = (unsigned short)rne16(v - bval(h));
}
__device__ __forceinline__ void bsplit2(float v0, float v1, unsigned& hi, unsigned& lo) {
  hi = pk2(v0, v1);
  lo = pk2(v0 - bval(hi & 0xffffu), v1 - bval(hi >> 16));
}
__device__ __forceinline__ int swzc(int col, int lr) {
  return (((col >> 3) ^ (lr & 7)) << 3) | (col & 7);
}

// ---- degree count ----------------------------------------------------------
__global__ void count_k(const int* __restrict__ ei, int* __restrict__ cnt, int E) {
  int e = blockIdx.x * 256 + threadIdx.x;
  if (e < E) atomicAdd(&cnt[ei[E + e]], 1);
}

// ---- 3-phase multi-block exclusive scan ------------------------------------
__global__ __launch_bounds__(512) void scanA_k(const int* __restrict__ cnt,
                                               int* __restrict__ bsum, int n) {
  __shared__ int ws[8];
  const int tid = threadIdx.x, lane = tid & 63, wid = tid >> 6;
  int i = blockIdx.x * 512 + tid;
  int v = (i < n) ? cnt[i] : 0;
#pragma unroll
  for (int off = 32; off > 0; off >>= 1) v += __shfl_xor(v, off);
  if (lane == 0) ws[wid] = v;
  __syncthreads();
  if (tid == 0) {
    int s = 0;
#pragma unroll
    for (int w = 0; w < 8; ++w) s += ws[w];
    bsum[blockIdx.x] = s;
  }
}

__global__ __launch_bounds__(128) void scanB_k(int* __restrict__ bsum, int nb) {
  __shared__ int w2[2];
  const int tid = threadIdx.x, lane = tid & 63, wid = tid >> 6;
  int v = (tid < nb) ? bsum[tid] : 0;
  int s = v;
#pragma unroll
  for (int off = 1; off < 64; off <<= 1) {
    int u = __shfl_up(s, off);
    if (lane >= off) s += u;
  }
  if (lane == 63) w2[wid] = s;
  __syncthreads();
  int add = (wid == 1) ? w2[0] : 0;
  if (tid < nb) bsum[tid] = s - v + add;
}

__global__ __launch_bounds__(512) void scanC_k(int* __restrict__ cnt, float* __restrict__ invd,
                                               const int* __restrict__ bsum, int n) {
  __shared__ int ws[8];
  const int tid = threadIdx.x, lane = tid & 63, wid = tid >> 6;
  int i = blockIdx.x * 512 + tid;
  int v = (i < n) ? cnt[i] : 0;
  int s = v;
#pragma unroll
  for (int off = 1; off < 64; off <<= 1) {
    int u = __shfl_up(s, off);
    if (lane >= off) s += u;
  }
  if (lane == 63) ws[wid] = s;
  __syncthreads();
  int wadd = 0;
  for (int w = 0; w < wid; ++w) wadd += ws[w];
  if (i < n) {
    cnt[i] = s - v + wadd + bsum[blockIdx.x];
    invd[i] = v > 0 ? 1.f / (float)v : 0.f;
  }
}

// ---- scatter into dst-sorted order + precompute dist -----------------------
__global__ void scatter_k(const int* __restrict__ ei, const float* __restrict__ pos,
                          int* __restrict__ cur, unsigned int* __restrict__ spk,
                          float4* __restrict__ dist4, int E) {
  int e = blockIdx.x * 256 + threadIdx.x;
  if (e >= E) return;
  int s = ei[e], d = ei[E + e];
  int p = atomicAdd(&cur[d], 1);
  spk[p] = (unsigned int)s | ((unsigned int)d << 16);
  float4 dv;
  dv.x = pos[(size_t)s*3+0] - pos[(size_t)d*3+0];
  dv.y = pos[(size_t)s*3+1] - pos[(size_t)d*3+1];
  dv.z = pos[(size_t)s*3+2] - pos[(size_t)d*3+2];
  dv.w = 0.f;
  dist4[p] = dv;
}

// ---- weight folding --------------------------------------------------------
__global__ void fold_all_k(const float* __restrict__ m3w2, const float* __restrict__ m2w1,
                           const float* __restrict__ m3b2, const float* __restrict__ m2b1,
                           const float* __restrict__ m2w2, const float* __restrict__ m1w1,
                           const float* __restrict__ m2b2,
                           float* __restrict__ Wf, float* __restrict__ ub,
                           float* __restrict__ Wm, float* __restrict__ bf) {
  const int k = blockIdx.x, l = blockIdx.y, mode = blockIdx.z, c = threadIdx.x;
  const float *A, *B, *bA, *badd;
  float *O, *ob;
  if (mode == 0) {
    A = m3w2 + (size_t)l * 128 * 128;
    B = m2w1 + (size_t)l * 256 * 128 + 128 * 128;
    bA = m3b2 + (size_t)l * 128; badd = m2b1 + (size_t)l * 128;
    O = Wf + (size_t)l * 128 * 128; ob = ub + (size_t)l * 128;
  } else {
    A = m2w2 + (size_t)l * 128 * 128;
    B = m1w1 + (size_t)l * 256 * 128;
    bA = m2b2 + (size_t)l * 128; badd = nullptr;
    O = Wm + (size_t)l * 128 * 128; ob = bf + (size_t)l * 128;
  }
  float s = 0.f;
  for (int r = 0; r < 128; ++r) s = fmaf(A[k * 128 + r], B[r * 128 + c], s);
  O[k * 128 + c] = s;
  if (k == 0) {
    float t = badd ? badd[c] : 0.f;
    for (int r = 0; r < 128; ++r) t = fmaf(bA[r], B[r * 128 + c], t);
    ob[c] = t;
  }
}

// ---- pack Wf into bf16 B-fragment order (edge kernel, hi only) -------------
__global__ void pack_k(const float* __restrict__ Wf, unsigned short* __restrict__ Wpk) {
  int l = blockIdx.y;
  int flat = blockIdx.x * 256 + threadIdx.x;
  int e = flat & 7, l6 = (flat >> 3) & 63, ct = (flat >> 9) & 7, kt = flat >> 12;
  int row = kt * 32 + ((l6 >> 4) << 3) + e;
  int col = ct * 16 + (l6 & 15);
  Wpk[(size_t)l * 16384 + flat] =
      (unsigned short)rne16(Wf[(size_t)l * 16384 + row * 128 + col]);
}

// ---- pack node-GEMM weights into hi/lo B-fragment buffers ------------------
struct PDesc { const float* w0; const float* w1; unsigned short* out; int kt; };
struct PArgs { PDesc d[10]; };

__global__ void packw_k(PArgs pa) {
  PDesc de = pa.d[blockIdx.y];
  int flat = blockIdx.x * 256 + threadIdx.x;
  int tot = de.kt * 4096;
  if (flat >= tot) return;
  int e = flat & 7, ln = (flat >> 3) & 63, ct = (flat >> 9) & 7, kt = flat >> 12;
  int row = kt * 32 + ((ln >> 4) << 3) + e;
  int col = ct * 16 + (ln & 15);
  float v = (row < 128) ? de.w0[(size_t)row * 128 + col]
                        : de.w1[(size_t)(row - 128) * 128 + col];
  unsigned short hi, lo;
  bsplit(v, hi, lo);
  de.out[flat] = hi;
  de.out[tot + flat] = lo;
}

// ---- pack l1w [128][64] f32 -> bf16 B-frags (4 ct groups, hi only) ---------
__global__ void packl1_k(const float* __restrict__ l1w, unsigned short* __restrict__ out) {
  int flat = blockIdx.x * 256 + threadIdx.x;   // 0..8191
  if (flat >= 8192) return;
  int e = flat & 7, ln = (flat >> 3) & 63, ct = (flat >> 9) & 3, kt = flat >> 11;
  int row = kt * 32 + ((ln >> 4) << 3) + e;
  int col = ct * 16 + (ln & 15);
  out[flat] = (unsigned short)rne16(l1w[(size_t)row * 64 + col]);
}

// ---- init GEMM: h = relu(x*aw+ab) @ Wn + bias -> planes ; fused hAb --------
__global__ __launch_bounds__(256) void init_k(
    const float* __restrict__ x, const unsigned short* __restrict__ Wn,
    const float* __restrict__ bias, const float* __restrict__ aw,
    const float* __restrict__ ab,
    unsigned short* __restrict__ outh, unsigned short* __restrict__ outl,
    const unsigned short* __restrict__ Wa, unsigned short* __restrict__ outA, int M)
{
  __shared__ __align__(16) unsigned short hT[64 * 128];
  const int tid = threadIdx.x;
  const int lane = tid & 63, w4 = tid >> 6;
  const int lrow = lane & 15, lk = lane >> 4;
  const int m0 = blockIdx.x * 64;
  const unsigned short* __restrict__ Wlo = Wn + 16384;

  const int rown = m0 + w4 * 16 + lrow;
  const bool valid = rown < M;
  const float xv = valid ? x[rown] : 0.f;

  f32x4 acc[8];
#pragma unroll
  for (int ct = 0; ct < 8; ++ct) acc[ct] = (f32x4){0.f, 0.f, 0.f, 0.f};

#pragma unroll
  for (int ktg = 0; ktg < 4; ++ktg) {
    const int k0 = ktg * 32 + lk * 8;
    float4 a0 = *(const float4*)&aw[k0];
    float4 a1 = *(const float4*)&aw[k0 + 4];
    float4 b0 = *(const float4*)&ab[k0];
    float4 b1 = *(const float4*)&ab[k0 + 4];
    float awv[8] = {a0.x,a0.y,a0.z,a0.w,a1.x,a1.y,a1.z,a1.w};
    float abv[8] = {b0.x,b0.y,b0.z,b0.w,b1.x,b1.y,b1.z,b1.w};
    unsigned h4[4], l4[4];
#pragma unroll
    for (int e = 0; e < 4; ++e) {
      float v0 = fmaf(xv, awv[e*2], abv[e*2]);
      float v1 = fmaf(xv, awv[e*2+1], abv[e*2+1]);
      v0 = v0 > 0.f ? v0 : 0.f;
      v1 = v1 > 0.f ? v1 : 0.f;
      bsplit2(v0, v1, h4[e], l4[e]);
    }
    bf16x8 ah = __builtin_bit_cast(bf16x8, *(uint4*)h4);
    bf16x8 al = __builtin_bit_cast(bf16x8, *(uint4*)l4);
#pragma unroll
    for (int ct = 0; ct < 8; ++ct) {
      const size_t boff = (size_t)(((ktg * 8 + ct) * 64) + lane) * 8;
      bf16x8 bh = *(const bf16x8*)&Wn[boff];
      bf16x8 bl = *(const bf16x8*)&Wlo[boff];
      acc[ct] = __builtin_amdgcn_mfma_f32_16x16x32_bf16(ah, bh, acc[ct], 0, 0, 0);
      acc[ct] = __builtin_amdgcn_mfma_f32_16x16x32_bf16(al, bh, acc[ct], 0, 0, 0);
      acc[ct] = __builtin_amdgcn_mfma_f32_16x16x32_bf16(ah, bl, acc[ct], 0, 0, 0);
    }
  }

  const int rbl = w4 * 16 + lk * 4;
#pragma unroll
  for (int ct = 0; ct < 8; ++ct) {
    int col = ct * 16 + lrow;
    float bv = bias[col];
#pragma unroll
    for (int reg = 0; reg < 4; ++reg) {
      int row = m0 + rbl + reg;
      if (row < M) {
        float v = acc[ct][reg] + bv;
        unsigned short hi, lo;
        bsplit(v, hi, lo);
        outh[(size_t)row * HD + col] = hi;
        outl[(size_t)row * HD + col] = lo;
        hT[(rbl + reg) * 128 + swzc(col, rbl + reg)] = hi;
      }
    }
  }

  const unsigned short* __restrict__ Walo = Wa + 16384;
  f32x4 ac2[8];
#pragma unroll
  for (int ct = 0; ct < 8; ++ct) ac2[ct] = (f32x4){0.f, 0.f, 0.f, 0.f};
#pragma unroll
  for (int ktg = 0; ktg < 4; ++ktg) {
    const int lr = w4 * 16 + lrow;
    const int kb = ktg * 4 + lk;
    bf16x8 a = *(const bf16x8*)&hT[lr * 128 + ((kb ^ (lr & 7)) << 3)];
#pragma unroll
    for (int ct = 0; ct < 8; ++ct) {
      const size_t boff = (size_t)(((ktg * 8 + ct) * 64) + lane) * 8;
      bf16x8 bh = *(const bf16x8*)&Wa[boff];
      bf16x8 bl = *(const bf16x8*)&Walo[boff];
      ac2[ct] = __builtin_amdgcn_mfma_f32_16x16x32_bf16(a, bh, ac2[ct], 0, 0, 0);
      ac2[ct] = __builtin_amdgcn_mfma_f32_16x16x32_bf16(a, bl, ac2[ct], 0, 0, 0);
    }
  }
#pragma unroll
  for (int ct = 0; ct < 8; ++ct) {
    int col = ct * 16 + lrow;
#pragma unroll
    for (int reg = 0; reg < 4; ++reg) {
      int row = m0 + rbl + reg;
      if (row < M) outA[(size_t)row * HD + col] = (unsigned short)rne16(ac2[ct][reg]);
    }
  }
}

// ---- fused layer kernel ------------------------------------------------------
template<bool LAST>
__global__ __launch_bounds__(256) void layer_k(
    float* __restrict__ Pagg,
    const unsigned short* __restrict__ hH, const unsigned short* __restrict__ hL,
    const float* __restrict__ invd,
    const unsigned short* __restrict__ Wcat, const float* __restrict__ b1,
    const float* __restrict__ bf,
    const unsigned short* __restrict__ W2, const float* __restrict__ b2,
    const unsigned short* __restrict__ Wa,
    unsigned short* __restrict__ hHo, unsigned short* __restrict__ hLo,
    unsigned short* __restrict__ outA,
    const unsigned short* __restrict__ Wl1, const float* __restrict__ l1b,
    const float* __restrict__ l2w, const float* __restrict__ l2b,
    float* __restrict__ ybuf, int M)
{
  __shared__ __align__(16) unsigned short tmpH[64 * 128];
  __shared__ __align__(16) unsigned short tmpL[64 * 128];
  const int tid = threadIdx.x;
  const int lane = tid & 63, w4 = tid >> 6;
  const int lrow = lane & 15, lk = lane >> 4;
  const int m0 = blockIdx.x * 64;

  const int rown = m0 + w4 * 16 + lrow;
  const bool valid = rown < M;
  const float scl = valid ? invd[rown] : 0.f;

  const unsigned short* __restrict__ Wclo = Wcat + 32768;
  f32x4 acc[8];
#pragma unroll
  for (int ct = 0; ct < 8; ++ct) acc[ct] = (f32x4){0.f, 0.f, 0.f, 0.f};

#pragma unroll
  for (int ktg = 0; ktg < 8; ++ktg) {
    const int k0 = ktg * 32 + lk * 8;
    bf16x8 ah, al;
    if (k0 >= 128) {
      if (valid) {
        ah = *(const bf16x8*)&hH[(size_t)rown * HD + (k0 - 128)];
        al = *(const bf16x8*)&hL[(size_t)rown * HD + (k0 - 128)];
      } else {
        ah = (bf16x8){0,0,0,0,0,0,0,0};
        al = (bf16x8){0,0,0,0,0,0,0,0};
      }
    } else {
      float v[8] = {0,0,0,0,0,0,0,0};
      if (valid) {
        const float* base = Pagg + (size_t)rown * HD + k0;
        float4 v0 = *(const float4*)base;
        float4 v1 = *(const float4*)(base + 4);
        v[0]=v0.x*scl; v[1]=v0.y*scl; v[2]=v0.z*scl; v[3]=v0.w*scl;
        v[4]=v1.x*scl; v[5]=v1.y*scl; v[6]=v1.z*scl; v[7]=v1.w*scl;
      }
      unsigned h4[4], l4[4];
#pragma unroll
      for (int e = 0; e < 4; ++e) bsplit2(v[e*2], v[e*2+1], h4[e], l4[e]);
      ah = __builtin_bit_cast(bf16x8, *(uint4*)h4);
      al = __builtin_bit_cast(bf16x8, *(uint4*)l4);
    }
#pragma unroll
    for (int ct = 0; ct < 8; ++ct) {
      const size_t boff = (size_t)(((ktg * 8 + ct) * 64) + lane) * 8;
      bf16x8 bh = *(const bf16x8*)&Wcat[boff];
      bf16x8 bl = *(const bf16x8*)&Wclo[boff];
      acc[ct] = __builtin_amdgcn_mfma_f32_16x16x32_bf16(ah, bh, acc[ct], 0, 0, 0);
      acc[ct] = __builtin_amdgcn_mfma_f32_16x16x32_bf16(al, bh, acc[ct], 0, 0, 0);
      acc[ct] = __builtin_amdgcn_mfma_f32_16x16x32_bf16(ah, bl, acc[ct], 0, 0, 0);
    }
  }

  const int rbl = w4 * 16 + lk * 4;
  float m2[4];
#pragma unroll
  for (int reg = 0; reg < 4; ++reg) {
    int row = m0 + rbl + reg;
    m2[reg] = (row < M && invd[row] > 0.f) ? 1.f : 0.f;
  }
#pragma unroll
  for (int ct = 0; ct < 8; ++ct) {
    int col = ct * 16 + lrow;
    float bv = b1[col], bfv = bf[col];
#pragma unroll
    for (int reg = 0; reg < 4; ++reg) {
      int lr = rbl + reg;
      float v = acc[ct][reg] + bv + m2[reg] * bfv;
      if (v < 0.f) v = 0.f;
      unsigned short hi, lo;
      bsplit(v, hi, lo);
      int sp = lr * 128 + swzc(col, lr);
      tmpH[sp] = hi;
      tmpL[sp] = lo;
    }
  }

  const unsigned short* __restrict__ W2lo = W2 + 16384;
  f32x4 ac2[8];
#pragma unroll
  for (int ct = 0; ct < 8; ++ct) ac2[ct] = (f32x4){0.f, 0.f, 0.f, 0.f};
#pragma unroll
  for (int ktg = 0; ktg < 4; ++ktg) {
    const int lr = w4 * 16 + lrow;
    const int off = lr * 128 + (((ktg * 4 + lk) ^ (lr & 7)) << 3);
    bf16x8 aH = *(const bf16x8*)&tmpH[off];
    bf16x8 aL = *(const bf16x8*)&tmpL[off];
#pragma unroll
    for (int ct = 0; ct < 8; ++ct) {
      const size_t boff = (size_t)(((ktg * 8 + ct) * 64) + lane) * 8;
      bf16x8 bh = *(const bf16x8*)&W2[boff];
      bf16x8 bl = *(const bf16x8*)&W2lo[boff];
      ac2[ct] = __builtin_amdgcn_mfma_f32_16x16x32_bf16(aH, bh, ac2[ct], 0, 0, 0);
      ac2[ct] = __builtin_amdgcn_mfma_f32_16x16x32_bf16(aL, bh, ac2[ct], 0, 0, 0);
      ac2[ct] = __builtin_amdgcn_mfma_f32_16x16x32_bf16(aH, bl, ac2[ct], 0, 0, 0);
    }
  }
#pragma unroll
  for (int ct = 0; ct < 8; ++ct) {
    int col = ct * 16 + lrow;
    float bv = b2[col];
#pragma unroll
    for (int reg = 0; reg < 4; ++reg) {
      int row = m0 + rbl + reg;
      if (row < M) {
        float v = ac2[ct][reg] + bv;
        if (v < 0.f) v = 0.f;
        unsigned short hi, lo;
        bsplit(v, hi, lo);
        hHo[(size_t)row * HD + col] = hi;
        hLo[(size_t)row * HD + col] = lo;
        int lr = rbl + reg;
        tmpL[lr * 128 + swzc(col, lr)] = hi;
      }
    }
  }

  if constexpr (!LAST) {
    const unsigned short* __restrict__ Walo = Wa + 16384;
    f32x4 ac3[8];
#pragma unroll
    for (int ct = 0; ct < 8; ++ct) ac3[ct] = (f32x4){0.f, 0.f, 0.f, 0.f};
#pragma unroll
    for (int ktg = 0; ktg < 4; ++ktg) {
      const int lr = w4 * 16 + lrow;
      bf16x8 a = *(const bf16x8*)&tmpL[lr * 128 + (((ktg * 4 + lk) ^ (lr & 7)) << 3)];
#pragma unroll
      for (int ct = 0; ct < 8; ++ct) {
        const size_t boff = (size_t)(((ktg * 8 + ct) * 64) + lane) * 8;
        bf16x8 bh = *(const bf16x8*)&Wa[boff];
        bf16x8 bl = *(const bf16x8*)&Walo[boff];
        ac3[ct] = __builtin_amdgcn_mfma_f32_16x16x32_bf16(a, bh, ac3[ct], 0, 0, 0);
        ac3[ct] = __builtin_amdgcn_mfma_f32_16x16x32_bf16(a, bl, ac3[ct], 0, 0, 0);
      }
    }
#pragma unroll
    for (int ct = 0; ct < 8; ++ct) {
      int col = ct * 16 + lrow;
#pragma unroll
      for (int reg = 0; reg < 4; ++reg) {
        int row = m0 + rbl + reg;
        if (row < M) outA[(size_t)row * HD + col] = (unsigned short)rne16(ac3[ct][reg]);
      }
    }
    if (valid) {
      const float4 z4 = {0.f, 0.f, 0.f, 0.f};
#pragma unroll
      for (int ktg = 0; ktg < 4; ++ktg) {
        const int k0 = ktg * 32 + lk * 8;
        *(float4*)&Pagg[(size_t)rown * HD + k0] = z4;
        *(float4*)&Pagg[(size_t)rown * HD + k0 + 4] = z4;
      }
    }
  } else {
    f32x4 ac3[4];
#pragma unroll
    for (int ct = 0; ct < 4; ++ct) ac3[ct] = (f32x4){0.f, 0.f, 0.f, 0.f};
#pragma unroll
    for (int ktg = 0; ktg < 4; ++ktg) {
      const int lr = w4 * 16 + lrow;
      bf16x8 a = *(const bf16x8*)&tmpL[lr * 128 + (((ktg * 4 + lk) ^ (lr & 7)) << 3)];
#pragma unroll
      for (int ct = 0; ct < 4; ++ct) {
        bf16x8 b = *(const bf16x8*)&Wl1[(size_t)(((ktg * 4 + ct) * 64) + lane) * 8];
        ac3[ct] = __builtin_amdgcn_mfma_f32_16x16x32_bf16(a, b, ac3[ct], 0, 0, 0);
      }
    }
    const float l2b0 = l2b[0];
    float yp[4] = {0.f, 0.f, 0.f, 0.f};
#pragma unroll
    for (int ct = 0; ct < 4; ++ct) {
      int col = ct * 16 + lrow;
      float bb = l1b[col], ww = l2w[col];
#pragma unroll
      for (int reg = 0; reg < 4; ++reg) {
        float z = ac3[ct][reg] + bb;
        yp[reg] = fmaf(z > 0.f ? z : 0.f, ww, yp[reg]);
      }
    }
#pragma unroll
    for (int reg = 0; reg < 4; ++reg) {
#pragma unroll
      for (int off = 1; off < 16; off <<= 1) yp[reg] += __shfl_xor(yp[reg], off);
      int row = m0 + rbl + reg;
      if (lrow == 0 && row < M) ybuf[row] = yp[reg] + l2b0;
    }
  }
}

// ---- fused edge kernel: dist precomputed, f32 u/P in LDS --------------------
__global__ __launch_bounds__(256, 3) void edge_k(
    const unsigned int* __restrict__ spk, const float4* __restrict__ dist4,
    const unsigned short* __restrict__ hAb,
    const float* __restrict__ w31, const float* __restrict__ b31,
    const unsigned short* __restrict__ Wpk, const float* __restrict__ ub,
    float* __restrict__ Pagg, int E, int nwg)
{
  __shared__ __align__(16) float Twf[64 * 128];  // u then P (f32)
  __shared__ int SD[64];
  __shared__ int segstart[68];
  __shared__ int segdst[68];
  __shared__ int sScal[4];
  const int tid = threadIdx.x;
  const int lane = tid & 63, w4 = tid >> 6;
  const int lrow = lane & 15, lk = lane >> 4;

  int b = blockIdx.x;
  int q = nwg >> 3, r = nwg & 7;
  int xcd = b & 7, sub = b >> 3;
  int wg = (xcd < r ? xcd * (q + 1) : r * (q + 1) + (xcd - r) * q) + sub;
  const int e0 = wg * 64;

  // stage 1: independent coalesced dist load; spk only where needed
  const int myedge = e0 + w4 * 16 + lrow;
  float4 dv = {0.f, 0.f, 0.f, 0.f};
  if (myedge < E) dv = dist4[myedge];
  if (lk == 0) {
    int d = (myedge < E) ? (int)(spk[myedge] >> 16) : -1;
    SD[w4 * 16 + lrow] = d;
  }
  if (tid == 0) sScal[0] = (e0 > 0) ? (int)(spk[e0-1] >> 16) : -2;
  if (tid == 1) sScal[1] = (e0 + 64 < E) ? (int)(spk[e0+64] >> 16) : -2;
  const float d0 = dv.x, d1 = dv.y, d2 = dv.z;

  bf16x8 ah[4];
#pragma unroll
  for (int kt = 0; kt < 4; ++kt) {
    const int k0 = kt * 32 + lk * 8;
    unsigned h4[4];
#pragma unroll
    for (int e = 0; e < 4; ++e) {
      int k = k0 + e * 2;
      float v0 = fmaf(d0, w31[k],   fmaf(d1, w31[128+k],   fmaf(d2, w31[256+k],   b31[k])));
      float v1 = fmaf(d0, w31[k+1], fmaf(d1, w31[128+k+1], fmaf(d2, w31[256+k+1], b31[k+1])));
      v0 = v0 > 0.f ? v0 : 0.f;
      v1 = v1 > 0.f ? v1 : 0.f;
      h4[e] = pk2(v0, v1);
    }
    ah[kt] = __builtin_bit_cast(bf16x8, *(uint4*)h4);
  }

  f32x4 acc[8];
#pragma unroll
  for (int ct = 0; ct < 8; ++ct) acc[ct] = (f32x4){0.f, 0.f, 0.f, 0.f};
#pragma unroll
  for (int kt = 0; kt < 4; ++kt) {
#pragma unroll
    for (int ct = 0; ct < 8; ++ct) {
      bf16x8 bq = *(const bf16x8*)&Wpk[(size_t)(((kt*8 + ct) * 64) + lane) * 8];
      acc[ct] = __builtin_amdgcn_mfma_f32_16x16x32_bf16(ah[kt], bq, acc[ct], 0, 0, 0);
    }
  }

  // u (f32) -> Twf as [e][c]
  {
    const int ebase = w4 * 16 + lk * 4;
#pragma unroll
    for (int ct = 0; ct < 8; ++ct) {
      int c = ct * 16 + lrow;
      Twf[(ebase+0)*128 + c] = acc[ct][0];
      Twf[(ebase+1)*128 + c] = acc[ct][1];
      Twf[(ebase+2)*128 + c] = acc[ct][2];
      Twf[(ebase+3)*128 + c] = acc[ct][3];
    }
  }

  const int typ = tid >> 4, tx = tid & 15;
  uint4 hv[4];
#pragma unroll
  for (int i = 0; i < 4; ++i) {
    int p = e0 + typ * 4 + i;
    unsigned pk = (p < E) ? spk[p] : 0u;
    hv[i] = *(const uint4*)&hAb[(size_t)(pk & 0xffffu) * HD + tx * 8];
  }
  __syncthreads();

  if (tid < 64) {
    int dd = SD[tid];
    bool head = (tid == 0) || (dd != SD[tid - 1]);
    unsigned long long bal = __ballot(head);
    int rank = __popcll(bal & ((1ull << lane) - 1));
    if (head) { segstart[rank] = tid; segdst[rank] = dd; }
    if (tid == 0) sScal[3] = __popcll(bal);
  }

  // P = relu(u + hA[src] + ub) in place (f32)
  {
    float4 u0 = *(const float4*)&ub[tx*8];
    float4 u1 = *(const float4*)&ub[tx*8+4];
    float ubv[8] = {u0.x,u0.y,u0.z,u0.w,u1.x,u1.y,u1.z,u1.w};
#pragma unroll
    for (int i = 0; i < 4; ++i) {
      int row = typ * 4 + i;
      float* rp = &Twf[row * 128 + tx*8];
      float4 ua = *(const float4*)rp;
      float4 ubq = *(const float4*)(rp + 4);
      float uvv[8] = {ua.x,ua.y,ua.z,ua.w,ubq.x,ubq.y,ubq.z,ubq.w};
      float hvv[8] = {blo(hv[i].x),bhi(hv[i].x),blo(hv[i].y),bhi(hv[i].y),
                      blo(hv[i].z),bhi(hv[i].z),blo(hv[i].w),bhi(hv[i].w)};
      float p[8];
#pragma unroll
      for (int j = 0; j < 8; ++j) {
        float v = uvv[j] + hvv[j] + ubv[j];
        p[j] = v > 0.f ? v : 0.f;
      }
      float4 s0 = {p[0], p[1], p[2], p[3]};
      float4 s1 = {p[4], p[5], p[6], p[7]};
      *(float4*)rp = s0;
      *(float4*)(rp + 4) = s1;
    }
  }
  __syncthreads();

  // segment reduce (f32 reads, 4-wide unroll)
  {
    const int nseg = sScal[3];
    const int dprev = sScal[0], dnext = sScal[1];
    for (int s = w4; s < nseg; s += 4) {
      int dst = segdst[s];
      if (dst < 0) continue;
      int r0 = segstart[s];
      int r1 = (s + 1 < nseg) ? segstart[s + 1] : 64;
      float sx = 0.f, sy = 0.f;
      int rr = r0;
      for (; rr + 4 <= r1; rr += 4) {
        float2 v0 = *(const float2*)&Twf[(rr+0) * 128 + lane * 2];
        float2 v1 = *(const float2*)&Twf[(rr+1) * 128 + lane * 2];
        float2 v2 = *(const float2*)&Twf[(rr+2) * 128 + lane * 2];
        float2 v3 = *(const float2*)&Twf[(rr+3) * 128 + lane * 2];
        sx += v0.x + v1.x + v2.x + v3.x;
        sy += v0.y + v1.y + v2.y + v3.y;
      }
      for (; rr < r1; ++rr) {
        float2 v = *(const float2*)&Twf[rr * 128 + lane * 2];
        sx += v.x; sy += v.y;
      }
      float* pp = &Pagg[(size_t)dst * HD + lane * 2];
      if (dst == dprev || dst == dnext) {
        atomicAdd(pp, sx);
        atomicAdd(pp + 1, sy);
      } else {
        float2 st = {sx, sy};
        *(float2*)pp = st;
      }
    }
  }
}

// ---- readout phase 2 --------------------------------------------------------
__global__ void readout2_k(const float* __restrict__ ybuf, const int* __restrict__ batch,
                           float* __restrict__ out, int n) {
  int t = blockIdx.x * 256 + threadIdx.x;
  int base = t * 8;
  if (base >= n) return;
  int bprev = batch[base];
  float s = ybuf[base];
  for (int i = 1; i < 8; ++i) {
    int idx = base + i;
    if (idx >= n) break;
    int bb = batch[idx];
    if (bb != bprev) { atomicAdd(&out[bprev], s); s = 0.f; bprev = bb; }
    s += ybuf[idx];
  }
  atomicAdd(&out[bprev], s);
}

extern "C" void kernel_launch(void* const* d_in, const int* in_sizes, int n_in,
                              void* d_out, int out_size, void* d_ws, size_t ws_size,
                              hipStream_t stream) {
  const float* x     = (const float*)d_in[0];
  const float* pos   = (const float*)d_in[1];
  const int*   ei    = (const int*)d_in[2];
  const int*   batch = (const int*)d_in[3];
  const float* nw1   = (const float*)d_in[4];
  const float* nb1   = (const float*)d_in[5];
  const float* nw2   = (const float*)d_in[6];
  const float* nb2   = (const float*)d_in[7];
  const float* m1w1  = (const float*)d_in[8];
  const float* m1b1  = (const float*)d_in[9];
  const float* m1w2  = (const float*)d_in[10];
  const float* m1b2  = (const float*)d_in[11];
  const float* m2w1  = (const float*)d_in[12];
  const float* m2b1  = (const float*)d_in[13];
  const float* m2w2  = (const float*)d_in[14];
  const float* m2b2  = (const float*)d_in[15];
  const float* m3w1  = (const float*)d_in[16];
  const float* m3b1  = (const float*)d_in[17];
  const float* m3w2  = (const float*)d_in[18];
  const float* m3b2  = (const float*)d_in[19];
  const float* l1w   = (const float*)d_in[20];
  const float* l1b   = (const float*)d_in[21];
  const float* l2w   = (const float*)d_in[22];
  const float* l2b   = (const float*)d_in[23];

  const int N = in_sizes[0];
  const int E = in_sizes[2] / 2;
  const int L = in_sizes[8] / (256 * 128);

  float* Pagg = (float*)d_ws;                                   // [N,128] f32
  unsigned int* spk = (unsigned int*)(Pagg + (size_t)N * HD);   // [E]
  int*   cnt  = (int*)(spk + E);                                // [N]
  float* invd = (float*)(cnt + N);                              // [N]
  float* Wf   = invd + N;                                       // [L,128,128]
  float* ub   = Wf + (size_t)L * 128 * 128;                     // [L,128]
  float* Wm   = ub + (size_t)L * 128;                           // [L,128,128]
  float* bfold= Wm + (size_t)L * 128 * 128;                     // [L,128]
  unsigned short* hAb = (unsigned short*)(bfold + (size_t)L * 128);  // [N,128]
  unsigned short* Wpk = hAb + (size_t)N * HD;                   // [L,16384]
  float* ybuf = (float*)(Wpk + (size_t)L * 16384);              // [N]
  int*   bsum = (int*)(ybuf + N);                               // [128]
  unsigned short* WnBase = (unsigned short*)(bsum + 128);
  unsigned short* WnInit = WnBase;
  unsigned short* WnW2a[3], *WnCat[3], *WnW2[3];
  unsigned short* Wl1;
  unsigned short* planes;
  {
    unsigned short* p = WnBase + 32768;
    for (int l = 0; l < 3; ++l) {
      WnW2a[l] = p; p += 32768;
      WnCat[l] = p; p += 65536;
      WnW2[l]  = p; p += 32768;
    }
    Wl1 = p; p += 8192;
    planes = p;
  }
  unsigned short* hH = planes;                 // [N,128]
  unsigned short* hL = hH + (size_t)N * HD;
  // dist4 after planes (16B-aligned region)
  float4* dist4 = (float4*)(((size_t)(hL + (size_t)N * HD) + 15) & ~(size_t)15);

  hipMemsetAsync(cnt, 0, (size_t)N * sizeof(int), stream);
  hipMemsetAsync(d_out, 0, (size_t)out_size * sizeof(float), stream);
  hipMemsetAsync(Pagg, 0, (size_t)N * HD * sizeof(float), stream);

  count_k<<<(E + 255) / 256, 256, 0, stream>>>(ei, cnt, E);
  const int nsb = (N + 511) / 512;
  scanA_k<<<nsb, 512, 0, stream>>>(cnt, bsum, N);
  scanB_k<<<1, 128, 0, stream>>>(bsum, nsb);
  scanC_k<<<nsb, 512, 0, stream>>>(cnt, invd, bsum, N);
  scatter_k<<<(E + 255) / 256, 256, 0, stream>>>(ei, pos, cnt, spk, dist4, E);
  fold_all_k<<<dim3(128, L, 2), 128, 0, stream>>>(m3w2, m2w1, m3b2, m2b1,
                                                  m2w2, m1w1, m2b2, Wf, ub, Wm, bfold);
  pack_k<<<dim3(64, L), 256, 0, stream>>>(Wf, Wpk);
  packl1_k<<<32, 256, 0, stream>>>(l1w, Wl1);

  {
    PArgs pa;
    pa.d[0] = {nw2, nullptr, WnInit, 4};
    for (int l = 0; l < L; ++l) {
      pa.d[1 + l * 3] = {m2w1 + (size_t)l * 256 * 128, nullptr, WnW2a[l], 4};
      pa.d[2 + l * 3] = {Wm + (size_t)l * 128 * 128,
                         m1w1 + (size_t)l * 256 * 128 + 128 * 128, WnCat[l], 8};
      pa.d[3 + l * 3] = {m1w2 + (size_t)l * 128 * 128, nullptr, WnW2[l], 4};
    }
    packw_k<<<dim3(128, 1 + L * 3), 256, 0, stream>>>(pa);
  }

  const int gblk = (N + 63) / 64;
  init_k<<<gblk, 256, 0, stream>>>(x, WnInit, nb2, nw1, nb1, hH, hL, WnW2a[0], hAb, N);

  const int nwg = (E + 63) / 64;
  for (int l = 0; l < L; ++l) {
    edge_k<<<nwg, 256, 0, stream>>>(
        spk, dist4, hAb,
        m3w1 + (size_t)l * 3 * 128, m3b1 + (size_t)l * 128,
        Wpk + (size_t)l * 16384, ub + (size_t)l * 128,
        Pagg, E, nwg);
    if (l + 1 < L) {
      layer_k<false><<<gblk, 256, 0, stream>>>(
          Pagg, hH, hL, invd, WnCat[l], m1b1 + (size_t)l * 128,
          bfold + (size_t)l * 128, WnW2[l], m1b2 + (size_t)l * 128,
          WnW2a[l + 1], hH, hL, hAb,
          nullptr, nullptr, nullptr, nullptr, nullptr, N);
    } else {
      layer_k<true><<<gblk, 256, 0, stream>>>(
          Pagg, hH, hL, invd, WnCat[l], m1b1 + (size_t)l * 128,
          bfold + (size_t)l * 128, WnW2[l], m1b2 + (size_t)l * 128,
          nullptr, hH, hL, nullptr,
          Wl1, l1b, l2w, l2b, ybuf, N);
    }
  }

  readout2_k<<<(N + 2047) / 2048, 256, 0, stream>>>(ybuf, batch, (float*)d_out, N);
}

// Round 15
// 549.308 us; speedup vs baseline: 1.2388x; 1.2388x over previous
//
#include <hip/hip_runtime.h>

#define HD 128

typedef __attribute__((ext_vector_type(8))) short bf16x8;
typedef __attribute__((ext_vector_type(4))) float f32x4;

// ---- bf16 helpers ----------------------------------------------------------
__device__ __forceinline__ unsigned rne16(float x) {
  unsigned u = __builtin_bit_cast(unsigned, x);
  return (u + 0x7fffu + ((u >> 16) & 1u)) >> 16;
}
__device__ __forceinline__ unsigned pk2(float a, float b) {  // HW v_cvt_pk_bf16_f32
  unsigned r;
  asm("v_cvt_pk_bf16_f32 %0, %1, %2" : "=v"(r) : "v"(a), "v"(b));
  return r;
}
__device__ __forceinline__ float blo(unsigned u) { return __builtin_bit_cast(float, u << 16); }
__device__ __forceinline__ float bhi(unsigned u) { return __builtin_bit_cast(float, u & 0xffff0000u); }
__device__ __forceinline__ float bval(unsigned h16) { return __builtin_bit_cast(float, h16 << 16); }

__device__ __forceinline__ void bsplit(float v, unsigned short& hi, unsigned short& lo) {
  unsigned h = rne16(v);
  hi = (unsigned short)h;
  lo = (unsigned short)rne16(v - bval(h));
}
__device__ __forceinline__ int swzc(int col, int lr) {
  return (((col >> 3) ^ (lr & 7)) << 3) | (col & 7);
}

// ---- degree count ----------------------------------------------------------
__global__ void count_k(const int* __restrict__ ei, int* __restrict__ cnt, int E) {
  int e = blockIdx.x * 256 + threadIdx.x;
  if (e < E) atomicAdd(&cnt[ei[E + e]], 1);
}

// ---- 3-phase multi-block exclusive scan ------------------------------------
__global__ __launch_bounds__(512) void scanA_k(const int* __restrict__ cnt,
                                               int* __restrict__ bsum, int n) {
  __shared__ int ws[8];
  const int tid = threadIdx.x, lane = tid & 63, wid = tid >> 6;
  int i = blockIdx.x * 512 + tid;
  int v = (i < n) ? cnt[i] : 0;
#pragma unroll
  for (int off = 32; off > 0; off >>= 1) v += __shfl_xor(v, off);
  if (lane == 0) ws[wid] = v;
  __syncthreads();
  if (tid == 0) {
    int s = 0;
#pragma unroll
    for (int w = 0; w < 8; ++w) s += ws[w];
    bsum[blockIdx.x] = s;
  }
}

__global__ __launch_bounds__(128) void scanB_k(int* __restrict__ bsum, int nb) {
  __shared__ int w2[2];
  const int tid = threadIdx.x, lane = tid & 63, wid = tid >> 6;
  int v = (tid < nb) ? bsum[tid] : 0;
  int s = v;
#pragma unroll
  for (int off = 1; off < 64; off <<= 1) {
    int u = __shfl_up(s, off);
    if (lane >= off) s += u;
  }
  if (lane == 63) w2[wid] = s;
  __syncthreads();
  int add = (wid == 1) ? w2[0] : 0;
  if (tid < nb) bsum[tid] = s - v + add;
}

__global__ __launch_bounds__(512) void scanC_k(int* __restrict__ cnt, float* __restrict__ invd,
                                               const int* __restrict__ bsum, int n) {
  __shared__ int ws[8];
  const int tid = threadIdx.x, lane = tid & 63, wid = tid >> 6;
  int i = blockIdx.x * 512 + tid;
  int v = (i < n) ? cnt[i] : 0;
  int s = v;
#pragma unroll
  for (int off = 1; off < 64; off <<= 1) {
    int u = __shfl_up(s, off);
    if (lane >= off) s += u;
  }
  if (lane == 63) ws[wid] = s;
  __syncthreads();
  int wadd = 0;
  for (int w = 0; w < wid; ++w) wadd += ws[w];
  if (i < n) {
    cnt[i] = s - v + wadd + bsum[blockIdx.x];
    invd[i] = v > 0 ? 1.f / (float)v : 0.f;
  }
}

// ---- scatter into dst-sorted order -----------------------------------------
__global__ void scatter_k(const int* __restrict__ ei, int* __restrict__ cur,
                          unsigned int* __restrict__ spk, int E) {
  int e = blockIdx.x * 256 + threadIdx.x;
  if (e >= E) return;
  int s = ei[e], d = ei[E + e];
  int p = atomicAdd(&cur[d], 1);
  spk[p] = (unsigned int)s | ((unsigned int)d << 16);
}

// ---- weight folding --------------------------------------------------------
__global__ void fold_all_k(const float* __restrict__ m3w2, const float* __restrict__ m2w1,
                           const float* __restrict__ m3b2, const float* __restrict__ m2b1,
                           const float* __restrict__ m2w2, const float* __restrict__ m1w1,
                           const float* __restrict__ m2b2,
                           float* __restrict__ Wf, float* __restrict__ ub,
                           float* __restrict__ Wm, float* __restrict__ bf) {
  const int k = blockIdx.x, l = blockIdx.y, mode = blockIdx.z, c = threadIdx.x;
  const float *A, *B, *bA, *badd;
  float *O, *ob;
  if (mode == 0) {
    A = m3w2 + (size_t)l * 128 * 128;
    B = m2w1 + (size_t)l * 256 * 128 + 128 * 128;
    bA = m3b2 + (size_t)l * 128; badd = m2b1 + (size_t)l * 128;
    O = Wf + (size_t)l * 128 * 128; ob = ub + (size_t)l * 128;
  } else {
    A = m2w2 + (size_t)l * 128 * 128;
    B = m1w1 + (size_t)l * 256 * 128;
    bA = m2b2 + (size_t)l * 128; badd = nullptr;
    O = Wm + (size_t)l * 128 * 128; ob = bf + (size_t)l * 128;
  }
  float s = 0.f;
  for (int r = 0; r < 128; ++r) s = fmaf(A[k * 128 + r], B[r * 128 + c], s);
  O[k * 128 + c] = s;
  if (k == 0) {
    float t = badd ? badd[c] : 0.f;
    for (int r = 0; r < 128; ++r) t = fmaf(bA[r], B[r * 128 + c], t);
    ob[c] = t;
  }
}

// ---- pack Wf into bf16 B-fragment order (edge kernel, hi only) -------------
__global__ void pack_k(const float* __restrict__ Wf, unsigned short* __restrict__ Wpk) {
  int l = blockIdx.y;
  int flat = blockIdx.x * 256 + threadIdx.x;
  int e = flat & 7, l6 = (flat >> 3) & 63, ct = (flat >> 9) & 7, kt = flat >> 12;
  int row = kt * 32 + ((l6 >> 4) << 3) + e;
  int col = ct * 16 + (l6 & 15);
  Wpk[(size_t)l * 16384 + flat] =
      (unsigned short)rne16(Wf[(size_t)l * 16384 + row * 128 + col]);
}

// ---- pack node-GEMM weights into bf16 B-fragment buffers (hi only) ---------
struct PDesc { const float* w0; const float* w1; unsigned short* out; int kt; };
struct PArgs { PDesc d[10]; };

__global__ void packw_k(PArgs pa) {
  PDesc de = pa.d[blockIdx.y];
  int flat = blockIdx.x * 256 + threadIdx.x;
  int tot = de.kt * 4096;
  if (flat >= tot) return;
  int e = flat & 7, ln = (flat >> 3) & 63, ct = (flat >> 9) & 7, kt = flat >> 12;
  int row = kt * 32 + ((ln >> 4) << 3) + e;
  int col = ct * 16 + (ln & 15);
  float v = (row < 128) ? de.w0[(size_t)row * 128 + col]
                        : de.w1[(size_t)(row - 128) * 128 + col];
  de.out[flat] = (unsigned short)rne16(v);
}

// ---- pack l1w [128][64] f32 -> bf16 B-frags (4 ct groups) ------------------
__global__ void packl1_k(const float* __restrict__ l1w, unsigned short* __restrict__ out) {
  int flat = blockIdx.x * 256 + threadIdx.x;   // 0..8191
  if (flat >= 8192) return;
  int e = flat & 7, ln = (flat >> 3) & 63, ct = (flat >> 9) & 3, kt = flat >> 11;
  int row = kt * 32 + ((ln >> 4) << 3) + e;
  int col = ct * 16 + (ln & 15);
  out[flat] = (unsigned short)rne16(l1w[(size_t)row * 64 + col]);
}

// ---- init GEMM (bf16): h = relu(x*aw+ab) @ Wn + bias -> hH ; fused hAb -----
__global__ __launch_bounds__(256) void init_k(
    const float* __restrict__ x, const unsigned short* __restrict__ Wn,
    const float* __restrict__ bias, const float* __restrict__ aw,
    const float* __restrict__ ab,
    unsigned short* __restrict__ outh,
    const unsigned short* __restrict__ Wa, unsigned short* __restrict__ outA, int M)
{
  __shared__ __align__(16) unsigned short hT[64 * 128];
  const int tid = threadIdx.x;
  const int lane = tid & 63, w4 = tid >> 6;
  const int lrow = lane & 15, lk = lane >> 4;
  const int m0 = blockIdx.x * 64;

  const int rown = m0 + w4 * 16 + lrow;
  const bool valid = rown < M;
  const float xv = valid ? x[rown] : 0.f;

  f32x4 acc[8];
#pragma unroll
  for (int ct = 0; ct < 8; ++ct) acc[ct] = (f32x4){0.f, 0.f, 0.f, 0.f};

#pragma unroll
  for (int ktg = 0; ktg < 4; ++ktg) {
    const int k0 = ktg * 32 + lk * 8;
    float4 a0 = *(const float4*)&aw[k0];
    float4 a1 = *(const float4*)&aw[k0 + 4];
    float4 b0 = *(const float4*)&ab[k0];
    float4 b1 = *(const float4*)&ab[k0 + 4];
    float awv[8] = {a0.x,a0.y,a0.z,a0.w,a1.x,a1.y,a1.z,a1.w};
    float abv[8] = {b0.x,b0.y,b0.z,b0.w,b1.x,b1.y,b1.z,b1.w};
    unsigned h4[4];
#pragma unroll
    for (int e = 0; e < 4; ++e) {
      float v0 = fmaf(xv, awv[e*2], abv[e*2]);
      float v1 = fmaf(xv, awv[e*2+1], abv[e*2+1]);
      v0 = v0 > 0.f ? v0 : 0.f;
      v1 = v1 > 0.f ? v1 : 0.f;
      h4[e] = pk2(v0, v1);
    }
    bf16x8 ah = __builtin_bit_cast(bf16x8, *(uint4*)h4);
#pragma unroll
    for (int ct = 0; ct < 8; ++ct) {
      bf16x8 bh = *(const bf16x8*)&Wn[(size_t)(((ktg * 8 + ct) * 64) + lane) * 8];
      acc[ct] = __builtin_amdgcn_mfma_f32_16x16x32_bf16(ah, bh, acc[ct], 0, 0, 0);
    }
  }

  const int rbl = w4 * 16 + lk * 4;
#pragma unroll
  for (int ct = 0; ct < 8; ++ct) {
    int col = ct * 16 + lrow;
    float bv = bias[col];
#pragma unroll
    for (int reg = 0; reg < 4; ++reg) {
      int row = m0 + rbl + reg;
      if (row < M) {
        unsigned short hi = (unsigned short)rne16(acc[ct][reg] + bv);
        outh[(size_t)row * HD + col] = hi;
        hT[(rbl + reg) * 128 + swzc(col, rbl + reg)] = hi;
      }
    }
  }

  f32x4 ac2[8];
#pragma unroll
  for (int ct = 0; ct < 8; ++ct) ac2[ct] = (f32x4){0.f, 0.f, 0.f, 0.f};
#pragma unroll
  for (int ktg = 0; ktg < 4; ++ktg) {
    const int lr = w4 * 16 + lrow;
    const int kb = ktg * 4 + lk;
    bf16x8 a = *(const bf16x8*)&hT[lr * 128 + ((kb ^ (lr & 7)) << 3)];
#pragma unroll
    for (int ct = 0; ct < 8; ++ct) {
      bf16x8 bh = *(const bf16x8*)&Wa[(size_t)(((ktg * 8 + ct) * 64) + lane) * 8];
      ac2[ct] = __builtin_amdgcn_mfma_f32_16x16x32_bf16(a, bh, ac2[ct], 0, 0, 0);
    }
  }
#pragma unroll
  for (int ct = 0; ct < 8; ++ct) {
    int col = ct * 16 + lrow;
#pragma unroll
    for (int reg = 0; reg < 4; ++reg) {
      int row = m0 + rbl + reg;
      if (row < M) outA[(size_t)row * HD + col] = (unsigned short)rne16(ac2[ct][reg]);
    }
  }
}

// ---- fused layer kernel (bf16 node GEMMs, single LDS tmp) -------------------
template<bool LAST>
__global__ __launch_bounds__(256) void layer_k(
    float* __restrict__ Pagg,
    const unsigned short* __restrict__ hH,
    const float* __restrict__ invd,
    const unsigned short* __restrict__ Wcat, const float* __restrict__ b1,
    const float* __restrict__ bf,
    const unsigned short* __restrict__ W2, const float* __restrict__ b2,
    const unsigned short* __restrict__ Wa,
    unsigned short* __restrict__ hHo,
    unsigned short* __restrict__ outA,
    const unsigned short* __restrict__ Wl1, const float* __restrict__ l1b,
    const float* __restrict__ l2w, const float* __restrict__ l2b,
    float* __restrict__ ybuf, int M)
{
  __shared__ __align__(16) unsigned short tmpH[64 * 128];
  const int tid = threadIdx.x;
  const int lane = tid & 63, w4 = tid >> 6;
  const int lrow = lane & 15, lk = lane >> 4;
  const int m0 = blockIdx.x * 64;

  const int rown = m0 + w4 * 16 + lrow;
  const bool valid = rown < M;
  const float scl = valid ? invd[rown] : 0.f;

  f32x4 acc[8];
#pragma unroll
  for (int ct = 0; ct < 8; ++ct) acc[ct] = (f32x4){0.f, 0.f, 0.f, 0.f};

#pragma unroll
  for (int ktg = 0; ktg < 8; ++ktg) {
    const int k0 = ktg * 32 + lk * 8;
    bf16x8 ah;
    if (k0 >= 128) {
      if (valid) ah = *(const bf16x8*)&hH[(size_t)rown * HD + (k0 - 128)];
      else ah = (bf16x8){0,0,0,0,0,0,0,0};
    } else {
      float v[8] = {0,0,0,0,0,0,0,0};
      if (valid) {
        const float* base = Pagg + (size_t)rown * HD + k0;
        float4 v0 = *(const float4*)base;
        float4 v1 = *(const float4*)(base + 4);
        v[0]=v0.x*scl; v[1]=v0.y*scl; v[2]=v0.z*scl; v[3]=v0.w*scl;
        v[4]=v1.x*scl; v[5]=v1.y*scl; v[6]=v1.z*scl; v[7]=v1.w*scl;
      }
      unsigned h4[4];
#pragma unroll
      for (int e = 0; e < 4; ++e) h4[e] = pk2(v[e*2], v[e*2+1]);
      ah = __builtin_bit_cast(bf16x8, *(uint4*)h4);
    }
#pragma unroll
    for (int ct = 0; ct < 8; ++ct) {
      bf16x8 bh = *(const bf16x8*)&Wcat[(size_t)(((ktg * 8 + ct) * 64) + lane) * 8];
      acc[ct] = __builtin_amdgcn_mfma_f32_16x16x32_bf16(ah, bh, acc[ct], 0, 0, 0);
    }
  }

  const int rbl = w4 * 16 + lk * 4;
  float m2[4];
#pragma unroll
  for (int reg = 0; reg < 4; ++reg) {
    int row = m0 + rbl + reg;
    m2[reg] = (row < M && invd[row] > 0.f) ? 1.f : 0.f;
  }
#pragma unroll
  for (int ct = 0; ct < 8; ++ct) {
    int col = ct * 16 + lrow;
    float bv = b1[col], bfv = bf[col];
#pragma unroll
    for (int reg = 0; reg < 4; ++reg) {
      int lr = rbl + reg;
      float v = acc[ct][reg] + bv + m2[reg] * bfv;
      if (v < 0.f) v = 0.f;
      tmpH[lr * 128 + swzc(col, lr)] = (unsigned short)rne16(v);
    }
  }

  f32x4 ac2[8];
#pragma unroll
  for (int ct = 0; ct < 8; ++ct) ac2[ct] = (f32x4){0.f, 0.f, 0.f, 0.f};
#pragma unroll
  for (int ktg = 0; ktg < 4; ++ktg) {
    const int lr = w4 * 16 + lrow;
    bf16x8 aH = *(const bf16x8*)&tmpH[lr * 128 + (((ktg * 4 + lk) ^ (lr & 7)) << 3)];
#pragma unroll
    for (int ct = 0; ct < 8; ++ct) {
      bf16x8 bh = *(const bf16x8*)&W2[(size_t)(((ktg * 8 + ct) * 64) + lane) * 8];
      ac2[ct] = __builtin_amdgcn_mfma_f32_16x16x32_bf16(aH, bh, ac2[ct], 0, 0, 0);
    }
  }
#pragma unroll
  for (int ct = 0; ct < 8; ++ct) {
    int col = ct * 16 + lrow;
    float bv = b2[col];
#pragma unroll
    for (int reg = 0; reg < 4; ++reg) {
      int row = m0 + rbl + reg;
      if (row < M) {
        float v = ac2[ct][reg] + bv;
        if (v < 0.f) v = 0.f;
        unsigned short hi = (unsigned short)rne16(v);
        hHo[(size_t)row * HD + col] = hi;
        int lr = rbl + reg;
        tmpH[lr * 128 + swzc(col, lr)] = hi;  // own rows; pass-2 reads done
      }
    }
  }

  if constexpr (!LAST) {
    f32x4 ac3[8];
#pragma unroll
    for (int ct = 0; ct < 8; ++ct) ac3[ct] = (f32x4){0.f, 0.f, 0.f, 0.f};
#pragma unroll
    for (int ktg = 0; ktg < 4; ++ktg) {
      const int lr = w4 * 16 + lrow;
      bf16x8 a = *(const bf16x8*)&tmpH[lr * 128 + (((ktg * 4 + lk) ^ (lr & 7)) << 3)];
#pragma unroll
      for (int ct = 0; ct < 8; ++ct) {
        bf16x8 bh = *(const bf16x8*)&Wa[(size_t)(((ktg * 8 + ct) * 64) + lane) * 8];
        ac3[ct] = __builtin_amdgcn_mfma_f32_16x16x32_bf16(a, bh, ac3[ct], 0, 0, 0);
      }
    }
#pragma unroll
    for (int ct = 0; ct < 8; ++ct) {
      int col = ct * 16 + lrow;
#pragma unroll
      for (int reg = 0; reg < 4; ++reg) {
        int row = m0 + rbl + reg;
        if (row < M) outA[(size_t)row * HD + col] = (unsigned short)rne16(ac3[ct][reg]);
      }
    }
    if (valid) {
      const float4 z4 = {0.f, 0.f, 0.f, 0.f};
#pragma unroll
      for (int ktg = 0; ktg < 4; ++ktg) {
        const int k0 = ktg * 32 + lk * 8;
        *(float4*)&Pagg[(size_t)rown * HD + k0] = z4;
        *(float4*)&Pagg[(size_t)rown * HD + k0 + 4] = z4;
      }
    }
  } else {
    f32x4 ac3[4];
#pragma unroll
    for (int ct = 0; ct < 4; ++ct) ac3[ct] = (f32x4){0.f, 0.f, 0.f, 0.f};
#pragma unroll
    for (int ktg = 0; ktg < 4; ++ktg) {
      const int lr = w4 * 16 + lrow;
      bf16x8 a = *(const bf16x8*)&tmpH[lr * 128 + (((ktg * 4 + lk) ^ (lr & 7)) << 3)];
#pragma unroll
      for (int ct = 0; ct < 4; ++ct) {
        bf16x8 b = *(const bf16x8*)&Wl1[(size_t)(((ktg * 4 + ct) * 64) + lane) * 8];
        ac3[ct] = __builtin_amdgcn_mfma_f32_16x16x32_bf16(a, b, ac3[ct], 0, 0, 0);
      }
    }
    const float l2b0 = l2b[0];
    float yp[4] = {0.f, 0.f, 0.f, 0.f};
#pragma unroll
    for (int ct = 0; ct < 4; ++ct) {
      int col = ct * 16 + lrow;
      float bb = l1b[col], ww = l2w[col];
#pragma unroll
      for (int reg = 0; reg < 4; ++reg) {
        float z = ac3[ct][reg] + bb;
        yp[reg] = fmaf(z > 0.f ? z : 0.f, ww, yp[reg]);
      }
    }
#pragma unroll
    for (int reg = 0; reg < 4; ++reg) {
#pragma unroll
      for (int off = 1; off < 16; off <<= 1) yp[reg] += __shfl_xor(yp[reg], off);
      int row = m0 + rbl + reg;
      if (lrow == 0 && row < M) ybuf[row] = yp[reg] + l2b0;
    }
  }
}

// ---- fused edge kernel (r13 structure): 64 edges/block, f32 u/P in LDS -----
__global__ __launch_bounds__(256, 3) void edge_k(
    const unsigned int* __restrict__ spk, const float* __restrict__ pos,
    const unsigned short* __restrict__ hAb,
    const float* __restrict__ w31, const float* __restrict__ b31,
    const unsigned short* __restrict__ Wpk, const float* __restrict__ ub,
    float* __restrict__ Pagg, int E, int nwg)
{
  __shared__ __align__(16) float Twf[64 * 128];  // u then P (f32)
  __shared__ int SD[64];
  __shared__ int segstart[68];
  __shared__ int segdst[68];
  __shared__ int sScal[4];
  const int tid = threadIdx.x;
  const int lane = tid & 63, w4 = tid >> 6;
  const int lrow = lane & 15, lk = lane >> 4;

  int b = blockIdx.x;
  int q = nwg >> 3, r = nwg & 7;
  int xcd = b & 7, sub = b >> 3;
  int wg = (xcd < r ? xcd * (q + 1) : r * (q + 1) + (xcd - r) * q) + sub;
  const int e0 = wg * 64;

  const int myedge = e0 + w4 * 16 + lrow;
  int d = -1;
  float d0 = 0.f, d1 = 0.f, d2 = 0.f;
  if (myedge < E) {
    unsigned pk = spk[myedge];
    int s = (int)(pk & 0xffffu);
    d = (int)(pk >> 16);
    d0 = pos[(size_t)s*3+0] - pos[(size_t)d*3+0];
    d1 = pos[(size_t)s*3+1] - pos[(size_t)d*3+1];
    d2 = pos[(size_t)s*3+2] - pos[(size_t)d*3+2];
  }
  if (lk == 0) SD[w4 * 16 + lrow] = d;
  if (tid == 0) sScal[0] = (e0 > 0) ? (int)(spk[e0-1] >> 16) : -2;
  if (tid == 1) sScal[1] = (e0 + 64 < E) ? (int)(spk[e0+64] >> 16) : -2;

  bf16x8 ah[4];
#pragma unroll
  for (int kt = 0; kt < 4; ++kt) {
    const int k0 = kt * 32 + lk * 8;
    unsigned h4[4];
#pragma unroll
    for (int e = 0; e < 4; ++e) {
      int k = k0 + e * 2;
      float v0 = fmaf(d0, w31[k],   fmaf(d1, w31[128+k],   fmaf(d2, w31[256+k],   b31[k])));
      float v1 = fmaf(d0, w31[k+1], fmaf(d1, w31[128+k+1], fmaf(d2, w31[256+k+1], b31[k+1])));
      v0 = v0 > 0.f ? v0 : 0.f;
      v1 = v1 > 0.f ? v1 : 0.f;
      h4[e] = pk2(v0, v1);
    }
    ah[kt] = __builtin_bit_cast(bf16x8, *(uint4*)h4);
  }

  f32x4 acc[8];
#pragma unroll
  for (int ct = 0; ct < 8; ++ct) acc[ct] = (f32x4){0.f, 0.f, 0.f, 0.f};
#pragma unroll
  for (int kt = 0; kt < 4; ++kt) {
#pragma unroll
    for (int ct = 0; ct < 8; ++ct) {
      bf16x8 bq = *(const bf16x8*)&Wpk[(size_t)(((kt*8 + ct) * 64) + lane) * 8];
      acc[ct] = __builtin_amdgcn_mfma_f32_16x16x32_bf16(ah[kt], bq, acc[ct], 0, 0, 0);
    }
  }

  {
    const int ebase = w4 * 16 + lk * 4;
#pragma unroll
    for (int ct = 0; ct < 8; ++ct) {
      int c = ct * 16 + lrow;
      Twf[(ebase+0)*128 + c] = acc[ct][0];
      Twf[(ebase+1)*128 + c] = acc[ct][1];
      Twf[(ebase+2)*128 + c] = acc[ct][2];
      Twf[(ebase+3)*128 + c] = acc[ct][3];
    }
  }

  const int typ = tid >> 4, tx = tid & 15;
  uint4 hv[4];
#pragma unroll
  for (int i = 0; i < 4; ++i) {
    int p = e0 + typ * 4 + i;
    unsigned pk = (p < E) ? spk[p] : 0u;
    hv[i] = *(const uint4*)&hAb[(size_t)(pk & 0xffffu) * HD + tx * 8];
  }
  __syncthreads();

  if (tid < 64) {
    int dd = SD[tid];
    bool head = (tid == 0) || (dd != SD[tid - 1]);
    unsigned long long bal = __ballot(head);
    int rank = __popcll(bal & ((1ull << lane) - 1));
    if (head) { segstart[rank] = tid; segdst[rank] = dd; }
    if (tid == 0) sScal[3] = __popcll(bal);
  }

  {
    float4 u0 = *(const float4*)&ub[tx*8];
    float4 u1 = *(const float4*)&ub[tx*8+4];
    float ubv[8] = {u0.x,u0.y,u0.z,u0.w,u1.x,u1.y,u1.z,u1.w};
#pragma unroll
    for (int i = 0; i < 4; ++i) {
      int row = typ * 4 + i;
      float* rp = &Twf[row * 128 + tx*8];
      float4 ua = *(const float4*)rp;
      float4 ubq = *(const float4*)(rp + 4);
      float uvv[8] = {ua.x,ua.y,ua.z,ua.w,ubq.x,ubq.y,ubq.z,ubq.w};
      float hvv[8] = {blo(hv[i].x),bhi(hv[i].x),blo(hv[i].y),bhi(hv[i].y),
                      blo(hv[i].z),bhi(hv[i].z),blo(hv[i].w),bhi(hv[i].w)};
      float p[8];
#pragma unroll
      for (int j = 0; j < 8; ++j) {
        float v = uvv[j] + hvv[j] + ubv[j];
        p[j] = v > 0.f ? v : 0.f;
      }
      float4 s0 = {p[0], p[1], p[2], p[3]};
      float4 s1 = {p[4], p[5], p[6], p[7]};
      *(float4*)rp = s0;
      *(float4*)(rp + 4) = s1;
    }
  }
  __syncthreads();

  {
    const int nseg = sScal[3];
    const int dprev = sScal[0], dnext = sScal[1];
    for (int s = w4; s < nseg; s += 4) {
      int dst = segdst[s];
      if (dst < 0) continue;
      int r0 = segstart[s];
      int r1 = (s + 1 < nseg) ? segstart[s + 1] : 64;
      float sx = 0.f, sy = 0.f;
      int rr = r0;
      for (; rr + 4 <= r1; rr += 4) {
        float2 v0 = *(const float2*)&Twf[(rr+0) * 128 + lane * 2];
        float2 v1 = *(const float2*)&Twf[(rr+1) * 128 + lane * 2];
        float2 v2 = *(const float2*)&Twf[(rr+2) * 128 + lane * 2];
        float2 v3 = *(const float2*)&Twf[(rr+3) * 128 + lane * 2];
        sx += v0.x + v1.x + v2.x + v3.x;
        sy += v0.y + v1.y + v2.y + v3.y;
      }
      for (; rr < r1; ++rr) {
        float2 v = *(const float2*)&Twf[rr * 128 + lane * 2];
        sx += v.x; sy += v.y;
      }
      float* pp = &Pagg[(size_t)dst * HD + lane * 2];
      if (dst == dprev || dst == dnext) {
        atomicAdd(pp, sx);
        atomicAdd(pp + 1, sy);
      } else {
        float2 st = {sx, sy};
        *(float2*)pp = st;
      }
    }
  }
}

// ---- readout phase 2 --------------------------------------------------------
__global__ void readout2_k(const float* __restrict__ ybuf, const int* __restrict__ batch,
                           float* __restrict__ out, int n) {
  int t = blockIdx.x * 256 + threadIdx.x;
  int base = t * 8;
  if (base >= n) return;
  int bprev = batch[base];
  float s = ybuf[base];
  for (int i = 1; i < 8; ++i) {
    int idx = base + i;
    if (idx >= n) break;
    int bb = batch[idx];
    if (bb != bprev) { atomicAdd(&out[bprev], s); s = 0.f; bprev = bb; }
    s += ybuf[idx];
  }
  atomicAdd(&out[bprev], s);
}

extern "C" void kernel_launch(void* const* d_in, const int* in_sizes, int n_in,
                              void* d_out, int out_size, void* d_ws, size_t ws_size,
                              hipStream_t stream) {
  const float* x     = (const float*)d_in[0];
  const float* pos   = (const float*)d_in[1];
  const int*   ei    = (const int*)d_in[2];
  const int*   batch = (const int*)d_in[3];
  const float* nw1   = (const float*)d_in[4];
  const float* nb1   = (const float*)d_in[5];
  const float* nw2   = (const float*)d_in[6];
  const float* nb2   = (const float*)d_in[7];
  const float* m1w1  = (const float*)d_in[8];
  const float* m1b1  = (const float*)d_in[9];
  const float* m1w2  = (const float*)d_in[10];
  const float* m1b2  = (const float*)d_in[11];
  const float* m2w1  = (const float*)d_in[12];
  const float* m2b1  = (const float*)d_in[13];
  const float* m2w2  = (const float*)d_in[14];
  const float* m2b2  = (const float*)d_in[15];
  const float* m3w1  = (const float*)d_in[16];
  const float* m3b1  = (const float*)d_in[17];
  const float* m3w2  = (const float*)d_in[18];
  const float* m3b2  = (const float*)d_in[19];
  const float* l1w   = (const float*)d_in[20];
  const float* l1b   = (const float*)d_in[21];
  const float* l2w   = (const float*)d_in[22];
  const float* l2b   = (const float*)d_in[23];

  const int N = in_sizes[0];
  const int E = in_sizes[2] / 2;
  const int L = in_sizes[8] / (256 * 128);

  float* Pagg = (float*)d_ws;                                   // [N,128] f32
  unsigned int* spk = (unsigned int*)(Pagg + (size_t)N * HD);   // [E]
  int*   cnt  = (int*)(spk + E);                                // [N]
  float* invd = (float*)(cnt + N);                              // [N]
  float* Wf   = invd + N;                                       // [L,128,128]
  float* ub   = Wf + (size_t)L * 128 * 128;                     // [L,128]
  float* Wm   = ub + (size_t)L * 128;                           // [L,128,128]
  float* bfold= Wm + (size_t)L * 128 * 128;                     // [L,128]
  unsigned short* hAb = (unsigned short*)(bfold + (size_t)L * 128);  // [N,128]
  unsigned short* Wpk = hAb + (size_t)N * HD;                   // [L,16384]
  float* ybuf = (float*)(Wpk + (size_t)L * 16384);              // [N]
  int*   bsum = (int*)(ybuf + N);                               // [128]
  unsigned short* WnBase = (unsigned short*)(bsum + 128);
  unsigned short* WnInit = WnBase;
  unsigned short* WnW2a[3], *WnCat[3], *WnW2[3];
  unsigned short* Wl1;
  unsigned short* planes;
  {
    unsigned short* p = WnBase + 16384;           // init: 4*4096 (hi only)
    for (int l = 0; l < 3; ++l) {
      WnW2a[l] = p; p += 16384;
      WnCat[l] = p; p += 32768;
      WnW2[l]  = p; p += 16384;
    }
    Wl1 = p; p += 8192;
    planes = p;
  }
  unsigned short* hH = planes;                 // [N,128]

  hipMemsetAsync(cnt, 0, (size_t)N * sizeof(int), stream);
  hipMemsetAsync(d_out, 0, (size_t)out_size * sizeof(float), stream);
  hipMemsetAsync(Pagg, 0, (size_t)N * HD * sizeof(float), stream);

  count_k<<<(E + 255) / 256, 256, 0, stream>>>(ei, cnt, E);
  const int nsb = (N + 511) / 512;
  scanA_k<<<nsb, 512, 0, stream>>>(cnt, bsum, N);
  scanB_k<<<1, 128, 0, stream>>>(bsum, nsb);
  scanC_k<<<nsb, 512, 0, stream>>>(cnt, invd, bsum, N);
  scatter_k<<<(E + 255) / 256, 256, 0, stream>>>(ei, cnt, spk, E);
  fold_all_k<<<dim3(128, L, 2), 128, 0, stream>>>(m3w2, m2w1, m3b2, m2b1,
                                                  m2w2, m1w1, m2b2, Wf, ub, Wm, bfold);
  pack_k<<<dim3(64, L), 256, 0, stream>>>(Wf, Wpk);
  packl1_k<<<32, 256, 0, stream>>>(l1w, Wl1);

  {
    PArgs pa;
    pa.d[0] = {nw2, nullptr, WnInit, 4};
    for (int l = 0; l < L; ++l) {
      pa.d[1 + l * 3] = {m2w1 + (size_t)l * 256 * 128, nullptr, WnW2a[l], 4};
      pa.d[2 + l * 3] = {Wm + (size_t)l * 128 * 128,
                         m1w1 + (size_t)l * 256 * 128 + 128 * 128, WnCat[l], 8};
      pa.d[3 + l * 3] = {m1w2 + (size_t)l * 128 * 128, nullptr, WnW2[l], 4};
    }
    packw_k<<<dim3(128, 1 + L * 3), 256, 0, stream>>>(pa);
  }

  const int gblk = (N + 63) / 64;
  init_k<<<gblk, 256, 0, stream>>>(x, WnInit, nb2, nw1, nb1, hH, WnW2a[0], hAb, N);

  const int nwg = (E + 63) / 64;
  for (int l = 0; l < L; ++l) {
    edge_k<<<nwg, 256, 0, stream>>>(
        spk, pos, hAb,
        m3w1 + (size_t)l * 3 * 128, m3b1 + (size_t)l * 128,
        Wpk + (size_t)l * 16384, ub + (size_t)l * 128,
        Pagg, E, nwg);
    if (l + 1 < L) {
      layer_k<false><<<gblk, 256, 0, stream>>>(
          Pagg, hH, invd, WnCat[l], m1b1 + (size_t)l * 128,
          bfold + (size_t)l * 128, WnW2[l], m1b2 + (size_t)l * 128,
          WnW2a[l + 1], hH, hAb,
          nullptr, nullptr, nullptr, nullptr, nullptr, N);
    } else {
      layer_k<true><<<gblk, 256, 0, stream>>>(
          Pagg, hH, invd, WnCat[l], m1b1 + (size_t)l * 128,
          bfold + (size_t)l * 128, WnW2[l], m1b2 + (size_t)l * 128,
          nullptr, hH, nullptr,
          Wl1, l1b, l2w, l2b, ybuf, N);
    }
  }

  readout2_k<<<(N + 2047) / 2048, 256, 0, stream>>>(ybuf, batch, (float*)d_out, N);
}